// Round 2
// baseline (2029.984 us; speedup 1.0000x reference)
//
#include <hip/hip_runtime.h>
#include <math.h>

#define Bb 4
#define Nn 2048
#define Ee 768
#define Hh 12
#define Dd 64
#define RD 32
#define EPSf 1e-6f
#define NEG_BIG -3.0e38f

__device__ inline float wave_reduce_sum(float v) {
    #pragma unroll
    for (int m = 1; m < 64; m <<= 1) v += __shfl_xor(v, m, 64);
    return v;
}
__device__ inline float wave_reduce_max(float v) {
    #pragma unroll
    for (int m = 1; m < 64; m <<= 1) v = fmaxf(v, __shfl_xor(v, m, 64));
    return v;
}

// Precompute rope/xpos coefficients per (n, pair i) in fp64, store fp32.
// idx = n*16 + i, i in [0,16).
__global__ void tab_kernel(float* __restrict__ ctab, float* __restrict__ stab,
                           float* __restrict__ sctab) {
    int idx = blockIdx.x * 256 + threadIdx.x;
    if (idx >= Nn * 16) return;
    int n = idx >> 4, i = idx & 15;
    double inv_freq = pow(10000.0, -(double)(2 * i) / (double)RD);
    double ang = (double)n * inv_freq;
    ctab[idx] = (float)cos(ang);
    stab[idx] = (float)sin(ang);
    double base = (2.0 * (double)i + 0.4 * (double)RD) / (1.4 * (double)RD);
    double pw = ((double)n - (double)(Nn / 2)) / 512.0;
    sctab[idx] = (float)pow(base, pw);
}

// One wave per (b,h,n) row: RMS-norm over D=64 (lane=dim), then xPos RoPE on
// first 32 dims via fp64-accurate tables. Writes (B,H,N,D); folds 0.125 into q.
__global__ __launch_bounds__(256) void prep_kernel(
    const float* __restrict__ q, const float* __restrict__ k,
    const float* __restrict__ qscale, const float* __restrict__ kscale,
    const float* __restrict__ ctab, const float* __restrict__ stab,
    const float* __restrict__ sctab,
    float* __restrict__ qn, float* __restrict__ kn)
{
    int wave = blockIdx.x * 4 + (threadIdx.x >> 6);
    int lane = threadIdx.x & 63;
    int n  = wave % Nn;
    int bh = wave / Nn;
    int h  = bh % Hh;
    int b  = bh / Hh;
    int gidx = (b * Nn + n) * Ee + h * Dd + lane;
    float xq = q[gidx], xk = k[gidx];
    float msq = wave_reduce_sum(xq * xq) * (1.0f / 64.0f);
    float msk = wave_reduce_sum(xk * xk) * (1.0f / 64.0f);
    float xqn = xq * qscale[lane] * rsqrtf(msq + EPSf);
    float xkn = xk * kscale[lane] * rsqrtf(msk + EPSf);
    float pq = __shfl_xor(xqn, 1, 64);   // pair partner
    float pk = __shfl_xor(xkn, 1, 64);
    float oq = xqn, ok = xkn;
    if (lane < RD) {
        int i = lane >> 1;
        float c  = ctab[n * 16 + i];
        float s  = stab[n * 16 + i];
        float sc = sctab[n * 16 + i];
        // rotate_half: out[2i] = -x[2i+1], out[2i+1] = x[2i]
        float rq = (lane & 1) ? pq : -pq;
        float rk = (lane & 1) ? pk : -pk;
        oq = (xqn * c + rq * s) * sc;
        ok = (xkn * c + rk * s) / sc;
    }
    oq *= 0.125f;   // 1/sqrt(D) folded into q
    size_t oidx = (size_t)bh * (Nn * Dd) + (size_t)n * Dd + lane;
    qn[oidx] = oq;
    kn[oidx] = ok;
}

// Flash attention, causal. Block = 4 waves; wave w handles q-row r0+w.
// K/V 64x64 fp32 in LDS pitch 65. No +/-inf anywhere; P broadcast via LDS.
#define KP 65
__global__ __launch_bounds__(256) void attn_kernel(
    const float* __restrict__ qn, const float* __restrict__ kn,
    const float* __restrict__ v, float* __restrict__ y)
{
    __shared__ float Kl[64 * KP];
    __shared__ float Vl[64 * KP];
    __shared__ float qs[4 * 64];
    __shared__ float Pl[4 * 64];
    int t = threadIdx.x;
    int w = t >> 6, lane = t & 63;
    int bh = blockIdx.y;
    int b = bh / Hh, h = bh % Hh;
    int r0 = blockIdx.x * 4;
    int r = r0 + w;
    const float* qbase = qn + (size_t)bh * Nn * Dd;
    const float* kbase = kn + (size_t)bh * Nn * Dd;
    qs[w * 64 + lane] = qbase[(size_t)r * Dd + lane];
    float m = NEG_BIG, l = 0.0f, acc = 0.0f;
    int ntiles = (r0 + 3) / 64 + 1;   // block-uniform (r0 % 4 == 0)
    const float4* v4 = (const float4*)v;
    for (int tile = 0; tile < ntiles; ++tile) {
        int j0 = tile * 64;
        const float4* k4 = (const float4*)(kbase + (size_t)j0 * Dd);
        #pragma unroll
        for (int p = 0; p < 4; ++p) {
            int fi = t + p * 256;              // 0..1023 float4s of 64x64 tile
            int j = fi >> 4, d4 = fi & 15;
            float4 kv = k4[fi];
            float4 vv = v4[(size_t)(b * Nn + j0 + j) * (Ee / 4) + h * (Dd / 4) + d4];
            int la = j * KP + d4 * 4;
            Kl[la + 0] = kv.x; Kl[la + 1] = kv.y; Kl[la + 2] = kv.z; Kl[la + 3] = kv.w;
            Vl[la + 0] = vv.x; Vl[la + 1] = vv.y; Vl[la + 2] = vv.z; Vl[la + 3] = vv.w;
        }
        __syncthreads();
        // scores: lane = key index j
        float s = 0.0f;
        #pragma unroll
        for (int d = 0; d < 64; ++d)
            s = fmaf(qs[w * 64 + d], Kl[lane * KP + d], s);
        if (j0 + lane > r) s = NEG_BIG;
        float mt = wave_reduce_max(s);
        float mn = fmaxf(m, mt);
        float p_ = expf(s - mn);       // masked lanes: expf(~-3e38) == 0
        float ls = wave_reduce_sum(p_);
        float alpha = expf(m - mn);    // first tile: expf(-3e38 - mt) == 0
        l = l * alpha + ls;
        acc *= alpha;
        m = mn;
        Pl[w * 64 + lane] = p_;
        __syncthreads();
        // PV: lane = output dim
        #pragma unroll
        for (int j = 0; j < 64; ++j)
            acc = fmaf(Pl[w * 64 + j], Vl[j * KP + lane], acc);
        __syncthreads();
    }
    y[(size_t)(b * Nn + r) * Ee + h * Dd + lane] = acc / l;
}

// out[m][e] = sum_f y[m][f] * W[e][f] + bias[e]   (NT GEMM, 8192x768x768)
__global__ __launch_bounds__(256) void proj_kernel(
    const float* __restrict__ y, const float* __restrict__ Wt,
    const float* __restrict__ bias, float* __restrict__ out)
{
    __shared__ float Al[64 * 33];
    __shared__ float Bl[64 * 33];
    int t = threadIdx.x;
    int tx = t & 15, ty = t >> 4;
    int e0 = blockIdx.x * 64, m0 = blockIdx.y * 64;
    float acc[4][4] = {};
    const float4* y4 = (const float4*)y;
    const float4* w4 = (const float4*)Wt;
    for (int k0 = 0; k0 < Ee; k0 += 32) {
        #pragma unroll
        for (int p = 0; p < 2; ++p) {
            int fi = t + p * 256;               // 0..511 float4s of 64x32 tile
            int row = fi >> 3, c4 = fi & 7;
            float4 av = y4[(size_t)(m0 + row) * (Ee / 4) + (k0 >> 2) + c4];
            float4 bv = w4[(size_t)(e0 + row) * (Ee / 4) + (k0 >> 2) + c4];
            int la = row * 33 + c4 * 4;
            Al[la + 0] = av.x; Al[la + 1] = av.y; Al[la + 2] = av.z; Al[la + 3] = av.w;
            Bl[la + 0] = bv.x; Bl[la + 1] = bv.y; Bl[la + 2] = bv.z; Bl[la + 3] = bv.w;
        }
        __syncthreads();
        #pragma unroll 8
        for (int kk = 0; kk < 32; ++kk) {
            float a[4], bb[4];
            #pragma unroll
            for (int i = 0; i < 4; ++i) a[i] = Al[(ty * 4 + i) * 33 + kk];
            #pragma unroll
            for (int j = 0; j < 4; ++j) bb[j] = Bl[(tx * 4 + j) * 33 + kk];
            #pragma unroll
            for (int i = 0; i < 4; ++i)
                #pragma unroll
                for (int j = 0; j < 4; ++j)
                    acc[i][j] = fmaf(a[i], bb[j], acc[i][j]);
        }
        __syncthreads();
    }
    #pragma unroll
    for (int i = 0; i < 4; ++i)
        #pragma unroll
        for (int j = 0; j < 4; ++j)
            out[(size_t)(m0 + ty * 4 + i) * Ee + e0 + tx * 4 + j] =
                acc[i][j] + bias[e0 + tx * 4 + j];
}

extern "C" void kernel_launch(void* const* d_in, const int* in_sizes, int n_in,
                              void* d_out, int out_size, void* d_ws, size_t ws_size,
                              hipStream_t stream) {
    const float* q      = (const float*)d_in[0];
    const float* k      = (const float*)d_in[1];
    const float* v      = (const float*)d_in[2];
    const float* qscale = (const float*)d_in[3];
    const float* kscale = (const float*)d_in[4];
    const float* projw  = (const float*)d_in[5];
    const float* projb  = (const float*)d_in[6];
    float* out = (float*)d_out;

    const size_t per = (size_t)Bb * Hh * Nn * Dd;   // 6291456 floats
    float* ws = (float*)d_ws;
    float* ctab  = ws;                    // 32768
    float* stab  = ws + 32768;
    float* sctab = ws + 65536;
    float* qn    = ws + 98304;
    float* kn    = qn + per;
    float* yatt  = kn + per;

    // 0) fp64-accurate rope/xpos tables
    tab_kernel<<<(Nn * 16 + 255) / 256, 256, 0, stream>>>(ctab, stab, sctab);

    // 1) RMS-norm + xPos RoPE
    prep_kernel<<<(Bb * Hh * Nn) / 4, 256, 0, stream>>>(
        q, k, qscale, kscale, ctab, stab, sctab, qn, kn);

    // 2) causal flash attention
    dim3 agrid(Nn / 4, Bb * Hh);
    attn_kernel<<<agrid, 256, 0, stream>>>(qn, kn, v, yatt);

    // 3) output projection
    dim3 ggrid(Ee / 64, (Bb * Nn) / 64);
    proj_kernel<<<ggrid, 256, 0, stream>>>(yatt, projw, projb, out);
}

// Round 3
// 438.020 us; speedup vs baseline: 4.6345x; 4.6345x over previous
//
#include <hip/hip_runtime.h>
#include <math.h>

#define Bb 4
#define Nn 2048
#define Ee 768
#define Hh 12
#define Dd 64
#define RD 32
#define EPSf 1e-6f
#define NEG_BIG -3.0e38f
#define PIT 72   // bf16 pitch for 64-wide LDS tiles (16B-aligned rows, pad 8)

typedef __attribute__((ext_vector_type(8))) short short8;
typedef __attribute__((ext_vector_type(4))) float f32x4;

__device__ inline float wave_reduce_sum(float v) {
    #pragma unroll
    for (int m = 1; m < 64; m <<= 1) v += __shfl_xor(v, m, 64);
    return v;
}

// round-to-nearest-even fp32 -> bf16 bits (inputs are clean probabilities)
__device__ inline unsigned f2bf(float x) {
    union { float f; unsigned u; } c; c.f = x;
    unsigned r = c.u + 0x7FFFu + ((c.u >> 16) & 1u);
    return r >> 16;
}

// fp64-accurate rope/xpos tables: idx = n*16 + i
__global__ void tab_kernel(float* __restrict__ ctab, float* __restrict__ stab,
                           float* __restrict__ sctab) {
    int idx = blockIdx.x * 256 + threadIdx.x;
    if (idx >= Nn * 16) return;
    int n = idx >> 4, i = idx & 15;
    double inv_freq = pow(10000.0, -(double)(2 * i) / (double)RD);
    double ang = (double)n * inv_freq;
    ctab[idx] = (float)cos(ang);
    stab[idx] = (float)sin(ang);
    double base = (2.0 * (double)i + 0.4 * (double)RD) / (1.4 * (double)RD);
    double pw = ((double)n - (double)(Nn / 2)) / 512.0;
    sctab[idx] = (float)pow(base, pw);
}

// One wave per (b,h,n): RMS-norm + xPos rope; writes bf16 (B,H,N,D). 0.125 folded into q.
__global__ __launch_bounds__(256) void prep_kernel(
    const float* __restrict__ q, const float* __restrict__ k,
    const float* __restrict__ qscale, const float* __restrict__ kscale,
    const float* __restrict__ ctab, const float* __restrict__ stab,
    const float* __restrict__ sctab,
    unsigned short* __restrict__ qn, unsigned short* __restrict__ kn)
{
    int wave = blockIdx.x * 4 + (threadIdx.x >> 6);
    int lane = threadIdx.x & 63;
    int n  = wave % Nn;
    int bh = wave / Nn;
    int h  = bh % Hh;
    int b  = bh / Hh;
    int gidx = (b * Nn + n) * Ee + h * Dd + lane;
    float xq = q[gidx], xk = k[gidx];
    float msq = wave_reduce_sum(xq * xq) * (1.0f / 64.0f);
    float msk = wave_reduce_sum(xk * xk) * (1.0f / 64.0f);
    float xqn = xq * qscale[lane] * rsqrtf(msq + EPSf);
    float xkn = xk * kscale[lane] * rsqrtf(msk + EPSf);
    float pq = __shfl_xor(xqn, 1, 64);
    float pk = __shfl_xor(xkn, 1, 64);
    float oq = xqn, ok = xkn;
    if (lane < RD) {
        int i = lane >> 1;
        float c  = ctab[n * 16 + i];
        float s  = stab[n * 16 + i];
        float sc = sctab[n * 16 + i];
        float rq = (lane & 1) ? pq : -pq;
        float rk = (lane & 1) ? pk : -pk;
        oq = (xqn * c + rq * s) * sc;
        ok = (xkn * c + rk * s) / sc;
    }
    oq *= 0.125f;
    size_t oidx = (size_t)bh * (Nn * Dd) + (size_t)n * Dd + lane;
    qn[oidx] = (unsigned short)f2bf(oq);
    kn[oidx] = (unsigned short)f2bf(ok);
}

// Transpose V: (B,N,E) fp32 -> (B,H,D,N) bf16
__global__ __launch_bounds__(256) void vt_kernel(
    const float* __restrict__ v, unsigned short* __restrict__ vt)
{
    __shared__ float Vl[64 * 65];
    int t = threadIdx.x;
    int bh = blockIdx.x >> 5;        // 32 n-tiles per bh
    int n0 = (blockIdx.x & 31) * 64;
    int b = bh / Hh, h = bh % Hh;
    const float4* v4 = (const float4*)v;
    #pragma unroll
    for (int c = 0; c < 4; ++c) {
        int idx = t + c * 256;               // 0..1023 float4s
        int n = idx >> 4, d4 = idx & 15;
        float4 vv = v4[(size_t)(b * Nn + n0 + n) * (Ee / 4) + h * 16 + d4];
        int la = n * 65 + d4 * 4;
        Vl[la] = vv.x; Vl[la + 1] = vv.y; Vl[la + 2] = vv.z; Vl[la + 3] = vv.w;
    }
    __syncthreads();
    #pragma unroll
    for (int c = 0; c < 16; ++c) {
        int linear = t + c * 256;            // 0..4095
        int d = linear >> 6, n = linear & 63;
        vt[((size_t)bh * Dd + d) * Nn + n0 + n] = (unsigned short)f2bf(Vl[n * 65 + d]);
    }
}

// MFMA flash attention (causal). Block: 4 waves x 16 q-rows = 64-row Q tile.
// S^T = K.Q^T (M=key,N=qrow), online softmax in-lane, O^T = V^T.P^T.
__global__ __launch_bounds__(256) void attn_kernel(
    const unsigned short* __restrict__ qn, const unsigned short* __restrict__ kn,
    const unsigned short* __restrict__ vt, float* __restrict__ y)
{
    __shared__ __align__(16) unsigned short Kl[64 * PIT];
    __shared__ __align__(16) unsigned short Vl[64 * PIT];   // V^T: [dim][key]
    __shared__ __align__(16) unsigned short Pl[4 * 16 * PIT];
    int t = threadIdx.x;
    int w = t >> 6, lane = t & 63;
    int quad = lane >> 4, col = lane & 15;
    int bh = blockIdx.y;
    int b = bh / Hh, h = bh % Hh;
    int qt = (int)gridDim.x - 1 - (int)blockIdx.x;   // heavy q-tiles dispatch first
    int q0 = qt * 64;
    int qrow = q0 + w * 16 + col;                    // lane's q-row (repl. x4 quads)

    const unsigned short* qp = qn + ((size_t)bh * Nn + qrow) * Dd;
    short8 qf0 = *(const short8*)(qp + quad * 8);          // B-frag kc=0
    short8 qf1 = *(const short8*)(qp + 32 + quad * 8);     // B-frag kc=1

    f32x4 O[4];
    #pragma unroll
    for (int i = 0; i < 4; ++i) O[i] = (f32x4){0.f, 0.f, 0.f, 0.f};
    float m = NEG_BIG, l = 0.0f;
    unsigned short* Plw = Pl + w * 16 * PIT;
    int ntiles = qt + 1;

    for (int tile = 0; tile < ntiles; ++tile) {
        int j0 = tile * 64;
        // stage K [key][d] and V^T [dim][key], 64x64 bf16 each, pitch 72
        #pragma unroll
        for (int c = 0; c < 2; ++c) {
            int id = t + c * 256;                 // 0..511 chunks of 8 bf16
            int row = id >> 3, e8 = (id & 7) * 8;
            uint4 kv = *(const uint4*)(kn + ((size_t)bh * Nn + j0 + row) * Dd + e8);
            *(uint4*)(Kl + row * PIT + e8) = kv;
            uint4 vv = *(const uint4*)(vt + ((size_t)bh * Dd + row) * Nn + j0 + e8);
            *(uint4*)(Vl + row * PIT + e8) = vv;
        }
        __syncthreads();

        // S^T = K . Q^T : 4 mt (keys) x 2 kc (head-dim)
        f32x4 S[4];
        #pragma unroll
        for (int i = 0; i < 4; ++i) S[i] = (f32x4){0.f, 0.f, 0.f, 0.f};
        {
            const unsigned short* kb = Kl + col * PIT + quad * 8;
            #pragma unroll
            for (int mt = 0; mt < 4; ++mt) {
                short8 a0 = *(const short8*)(kb + mt * 16 * PIT);
                S[mt] = __builtin_amdgcn_mfma_f32_16x16x32_bf16(a0, qf0, S[mt], 0, 0, 0);
                short8 a1 = *(const short8*)(kb + mt * 16 * PIT + 32);
                S[mt] = __builtin_amdgcn_mfma_f32_16x16x32_bf16(a1, qf1, S[mt], 0, 0, 0);
            }
        }
        // causal mask: frag elem (key = j0+mt*16+quad*4+r, qrow=col)
        if (j0 + 63 > q0 + w * 16) {
            #pragma unroll
            for (int mt = 0; mt < 4; ++mt)
                #pragma unroll
                for (int r = 0; r < 4; ++r) {
                    int key = j0 + mt * 16 + quad * 4 + r;
                    if (key > qrow) S[mt][r] = NEG_BIG;
                }
        }
        // online softmax: lane holds 16 keys of ONE q-row; finish across quads
        float rmax = S[0][0];
        #pragma unroll
        for (int mt = 0; mt < 4; ++mt)
            #pragma unroll
            for (int r = 0; r < 4; ++r) rmax = fmaxf(rmax, S[mt][r]);
        rmax = fmaxf(rmax, __shfl_xor(rmax, 16, 64));
        rmax = fmaxf(rmax, __shfl_xor(rmax, 32, 64));
        float mn = fmaxf(m, rmax);
        float alpha = __expf(m - mn);
        float P[4][4];
        float rsum = 0.0f;
        #pragma unroll
        for (int mt = 0; mt < 4; ++mt)
            #pragma unroll
            for (int r = 0; r < 4; ++r) {
                P[mt][r] = __expf(S[mt][r] - mn);
                rsum += P[mt][r];
            }
        rsum += __shfl_xor(rsum, 16, 64);
        rsum += __shfl_xor(rsum, 32, 64);
        l = l * alpha + rsum;
        m = mn;
        #pragma unroll
        for (int i = 0; i < 4; ++i) O[i] *= alpha;
        // P -> LDS row-major [qrow][key] (own region; no block barrier needed)
        #pragma unroll
        for (int mt = 0; mt < 4; ++mt) {
            uint2 uu;
            uu.x = f2bf(P[mt][0]) | (f2bf(P[mt][1]) << 16);
            uu.y = f2bf(P[mt][2]) | (f2bf(P[mt][3]) << 16);
            *(uint2*)(Plw + col * PIT + mt * 16 + quad * 4) = uu;
        }
        asm volatile("s_waitcnt lgkmcnt(0)" ::: "memory");
        short8 pf0 = *(const short8*)(Plw + col * PIT + quad * 8);
        short8 pf1 = *(const short8*)(Plw + col * PIT + 32 + quad * 8);
        // O^T += V^T . P^T : 4 mt (dims) x 2 kc (keys)
        {
            const unsigned short* vb = Vl + col * PIT + quad * 8;
            #pragma unroll
            for (int mt = 0; mt < 4; ++mt) {
                short8 a0 = *(const short8*)(vb + mt * 16 * PIT);
                O[mt] = __builtin_amdgcn_mfma_f32_16x16x32_bf16(a0, pf0, O[mt], 0, 0, 0);
                short8 a1 = *(const short8*)(vb + mt * 16 * PIT + 32);
                O[mt] = __builtin_amdgcn_mfma_f32_16x16x32_bf16(a1, pf1, O[mt], 0, 0, 0);
            }
        }
        __syncthreads();
    }
    float rl = 1.0f / l;
    #pragma unroll
    for (int mt = 0; mt < 4; ++mt) {
        f32x4 o = O[mt] * rl;    // dims mt*16+quad*4 .. +3 of q-row `qrow`
        *(f32x4*)(y + ((size_t)b * Nn + qrow) * Ee + h * Dd + mt * 16 + quad * 4) = o;
    }
}

// out[m][e] = sum_f y[m][f] * W[e][f] + bias[e]   (NT GEMM, 8192x768x768, fp32)
__global__ __launch_bounds__(256) void proj_kernel(
    const float* __restrict__ y, const float* __restrict__ Wt,
    const float* __restrict__ bias, float* __restrict__ out)
{
    __shared__ float Al[64 * 33];
    __shared__ float Bl[64 * 33];
    int t = threadIdx.x;
    int tx = t & 15, ty = t >> 4;
    int e0 = blockIdx.x * 64, m0 = blockIdx.y * 64;
    float acc[4][4] = {};
    const float4* y4 = (const float4*)y;
    const float4* w4 = (const float4*)Wt;
    for (int k0 = 0; k0 < Ee; k0 += 32) {
        #pragma unroll
        for (int p = 0; p < 2; ++p) {
            int fi = t + p * 256;
            int row = fi >> 3, c4 = fi & 7;
            float4 av = y4[(size_t)(m0 + row) * (Ee / 4) + (k0 >> 2) + c4];
            float4 bv = w4[(size_t)(e0 + row) * (Ee / 4) + (k0 >> 2) + c4];
            int la = row * 33 + c4 * 4;
            Al[la] = av.x; Al[la + 1] = av.y; Al[la + 2] = av.z; Al[la + 3] = av.w;
            Bl[la] = bv.x; Bl[la + 1] = bv.y; Bl[la + 2] = bv.z; Bl[la + 3] = bv.w;
        }
        __syncthreads();
        #pragma unroll 8
        for (int kk = 0; kk < 32; ++kk) {
            float a[4], bb[4];
            #pragma unroll
            for (int i = 0; i < 4; ++i) a[i] = Al[(ty * 4 + i) * 33 + kk];
            #pragma unroll
            for (int j = 0; j < 4; ++j) bb[j] = Bl[(tx * 4 + j) * 33 + kk];
            #pragma unroll
            for (int i = 0; i < 4; ++i)
                #pragma unroll
                for (int j = 0; j < 4; ++j)
                    acc[i][j] = fmaf(a[i], bb[j], acc[i][j]);
        }
        __syncthreads();
    }
    #pragma unroll
    for (int i = 0; i < 4; ++i)
        #pragma unroll
        for (int j = 0; j < 4; ++j)
            out[(size_t)(m0 + ty * 4 + i) * Ee + e0 + tx * 4 + j] =
                acc[i][j] + bias[e0 + tx * 4 + j];
}

extern "C" void kernel_launch(void* const* d_in, const int* in_sizes, int n_in,
                              void* d_out, int out_size, void* d_ws, size_t ws_size,
                              hipStream_t stream) {
    const float* q      = (const float*)d_in[0];
    const float* k      = (const float*)d_in[1];
    const float* v      = (const float*)d_in[2];
    const float* qscale = (const float*)d_in[3];
    const float* kscale = (const float*)d_in[4];
    const float* projw  = (const float*)d_in[5];
    const float* projb  = (const float*)d_in[6];
    float* out = (float*)d_out;

    char* base = (char*)d_ws;
    float* ctab  = (float*)(base);                       // 128 KB
    float* stab  = (float*)(base + 131072);
    float* sctab = (float*)(base + 262144);
    unsigned short* qn = (unsigned short*)(base + 393216);        // 12 MB bf16
    unsigned short* kn = (unsigned short*)(base + 12976128);
    unsigned short* vt = (unsigned short*)(base + 25559040);
    float* yatt        = (float*)(base + 38141952);               // 24 MB fp32

    tab_kernel<<<(Nn * 16 + 255) / 256, 256, 0, stream>>>(ctab, stab, sctab);
    prep_kernel<<<(Bb * Hh * Nn) / 4, 256, 0, stream>>>(
        q, k, qscale, kscale, ctab, stab, sctab, qn, kn);
    vt_kernel<<<Bb * Hh * 32, 256, 0, stream>>>(v, vt);

    dim3 agrid(Nn / 64, Bb * Hh);                        // (32, 48)
    attn_kernel<<<agrid, 256, 0, stream>>>(qn, kn, vt, yatt);

    dim3 ggrid(Ee / 64, (Bb * Nn) / 64);                 // (12, 128)
    proj_kernel<<<ggrid, 256, 0, stream>>>(yatt, projw, projb, out);
}

// Round 4
// 281.372 us; speedup vs baseline: 7.2146x; 1.5567x over previous
//
#include <hip/hip_runtime.h>
#include <math.h>

#define Bb 4
#define Nn 2048
#define Ee 768
#define Hh 12
#define Dd 64
#define RD 32
#define EPSf 1e-6f
#define NEG_BIG -3.0e38f
#define PIT 72   // bf16 pitch for 64-wide LDS tiles (16B-aligned rows, pad 8)

typedef __attribute__((ext_vector_type(8))) short short8;
typedef __attribute__((ext_vector_type(4))) float f32x4;

__device__ inline float wave_reduce_sum(float v) {
    #pragma unroll
    for (int m = 1; m < 64; m <<= 1) v += __shfl_xor(v, m, 64);
    return v;
}

// round-to-nearest-even fp32 -> bf16 bits
__device__ inline unsigned f2bf(float x) {
    union { float f; unsigned u; } c; c.f = x;
    unsigned r = c.u + 0x7FFFu + ((c.u >> 16) & 1u);
    return r >> 16;
}

// fp64-accurate rope/xpos tables: idx = n*16 + i
__global__ void tab_kernel(float* __restrict__ ctab, float* __restrict__ stab,
                           float* __restrict__ sctab) {
    int idx = blockIdx.x * 256 + threadIdx.x;
    if (idx >= Nn * 16) return;
    int n = idx >> 4, i = idx & 15;
    double inv_freq = pow(10000.0, -(double)(2 * i) / (double)RD);
    double ang = (double)n * inv_freq;
    ctab[idx] = (float)cos(ang);
    stab[idx] = (float)sin(ang);
    double base = (2.0 * (double)i + 0.4 * (double)RD) / (1.4 * (double)RD);
    double pw = ((double)n - (double)(Nn / 2)) / 512.0;
    sctab[idx] = (float)pow(base, pw);
}

// One wave per (b,h,n): RMS-norm + xPos rope; writes bf16 (B,H,N,D). 0.125 folded into q.
__global__ __launch_bounds__(256) void prep_kernel(
    const float* __restrict__ q, const float* __restrict__ k,
    const float* __restrict__ qscale, const float* __restrict__ kscale,
    const float* __restrict__ ctab, const float* __restrict__ stab,
    const float* __restrict__ sctab,
    unsigned short* __restrict__ qn, unsigned short* __restrict__ kn)
{
    int wave = blockIdx.x * 4 + (threadIdx.x >> 6);
    int lane = threadIdx.x & 63;
    int n  = wave % Nn;
    int bh = wave / Nn;
    int h  = bh % Hh;
    int b  = bh / Hh;
    int gidx = (b * Nn + n) * Ee + h * Dd + lane;
    float xq = q[gidx], xk = k[gidx];
    float msq = wave_reduce_sum(xq * xq) * (1.0f / 64.0f);
    float msk = wave_reduce_sum(xk * xk) * (1.0f / 64.0f);
    float xqn = xq * qscale[lane] * rsqrtf(msq + EPSf);
    float xkn = xk * kscale[lane] * rsqrtf(msk + EPSf);
    float pq = __shfl_xor(xqn, 1, 64);
    float pk = __shfl_xor(xkn, 1, 64);
    float oq = xqn, ok = xkn;
    if (lane < RD) {
        int i = lane >> 1;
        float c  = ctab[n * 16 + i];
        float s  = stab[n * 16 + i];
        float sc = sctab[n * 16 + i];
        float rq = (lane & 1) ? pq : -pq;
        float rk = (lane & 1) ? pk : -pk;
        oq = (xqn * c + rq * s) * sc;
        ok = (xkn * c + rk * s) / sc;
    }
    oq *= 0.125f;
    size_t oidx = (size_t)bh * (Nn * Dd) + (size_t)n * Dd + lane;
    qn[oidx] = (unsigned short)f2bf(oq);
    kn[oidx] = (unsigned short)f2bf(ok);
}

// Transpose V: (B,N,E) fp32 -> (B,H,D,N) bf16
__global__ __launch_bounds__(256) void vt_kernel(
    const float* __restrict__ v, unsigned short* __restrict__ vt)
{
    __shared__ float Vl[64 * 65];
    int t = threadIdx.x;
    int bh = blockIdx.x >> 5;        // 32 n-tiles per bh
    int n0 = (blockIdx.x & 31) * 64;
    int b = bh / Hh, h = bh % Hh;
    const float4* v4 = (const float4*)v;
    #pragma unroll
    for (int c = 0; c < 4; ++c) {
        int idx = t + c * 256;               // 0..1023 float4s
        int n = idx >> 4, d4 = idx & 15;
        float4 vv = v4[(size_t)(b * Nn + n0 + n) * (Ee / 4) + h * 16 + d4];
        int la = n * 65 + d4 * 4;
        Vl[la] = vv.x; Vl[la + 1] = vv.y; Vl[la + 2] = vv.z; Vl[la + 3] = vv.w;
    }
    __syncthreads();
    #pragma unroll
    for (int c = 0; c < 16; ++c) {
        int linear = t + c * 256;            // 0..4095
        int d = linear >> 6, n = linear & 63;
        vt[((size_t)bh * Dd + d) * Nn + n0 + n] = (unsigned short)f2bf(Vl[n * 65 + d]);
    }
}

// W (E,E) fp32 -> bf16
__global__ __launch_bounds__(256) void wcvt_kernel(
    const float* __restrict__ w, unsigned short* __restrict__ wb)
{
    int idx = blockIdx.x * 256 + threadIdx.x;   // one float4 each
    float4 v = ((const float4*)w)[idx];
    uint2 uu;
    uu.x = f2bf(v.x) | (f2bf(v.y) << 16);
    uu.y = f2bf(v.z) | (f2bf(v.w) << 16);
    *(uint2*)(wb + (size_t)idx * 4) = uu;
}

// MFMA flash attention (causal). Block: 4 waves x 16 q-rows = 64-row Q tile.
// S^T = K.Q^T (M=key,N=qrow), online softmax in-lane, O^T = V^T.P^T.
// Writes y as bf16 (B,N,E).
__global__ __launch_bounds__(256) void attn_kernel(
    const unsigned short* __restrict__ qn, const unsigned short* __restrict__ kn,
    const unsigned short* __restrict__ vt, unsigned short* __restrict__ y)
{
    __shared__ __align__(16) unsigned short Kl[64 * PIT];
    __shared__ __align__(16) unsigned short Vl[64 * PIT];   // V^T: [dim][key]
    __shared__ __align__(16) unsigned short Pl[4 * 16 * PIT];
    int t = threadIdx.x;
    int w = t >> 6, lane = t & 63;
    int quad = lane >> 4, col = lane & 15;
    int bh = blockIdx.y;
    int b = bh / Hh, h = bh % Hh;
    int qt = (int)gridDim.x - 1 - (int)blockIdx.x;   // heavy q-tiles dispatch first
    int q0 = qt * 64;
    int qrow = q0 + w * 16 + col;

    const unsigned short* qp = qn + ((size_t)bh * Nn + qrow) * Dd;
    short8 qf0 = *(const short8*)(qp + quad * 8);
    short8 qf1 = *(const short8*)(qp + 32 + quad * 8);

    f32x4 O[4];
    #pragma unroll
    for (int i = 0; i < 4; ++i) O[i] = (f32x4){0.f, 0.f, 0.f, 0.f};
    float m = NEG_BIG, l = 0.0f;
    unsigned short* Plw = Pl + w * 16 * PIT;
    int ntiles = qt + 1;

    for (int tile = 0; tile < ntiles; ++tile) {
        int j0 = tile * 64;
        #pragma unroll
        for (int c = 0; c < 2; ++c) {
            int id = t + c * 256;
            int row = id >> 3, e8 = (id & 7) * 8;
            uint4 kv = *(const uint4*)(kn + ((size_t)bh * Nn + j0 + row) * Dd + e8);
            *(uint4*)(Kl + row * PIT + e8) = kv;
            uint4 vv = *(const uint4*)(vt + ((size_t)bh * Dd + row) * Nn + j0 + e8);
            *(uint4*)(Vl + row * PIT + e8) = vv;
        }
        __syncthreads();

        f32x4 S[4];
        #pragma unroll
        for (int i = 0; i < 4; ++i) S[i] = (f32x4){0.f, 0.f, 0.f, 0.f};
        {
            const unsigned short* kb = Kl + col * PIT + quad * 8;
            #pragma unroll
            for (int mt = 0; mt < 4; ++mt) {
                short8 a0 = *(const short8*)(kb + mt * 16 * PIT);
                S[mt] = __builtin_amdgcn_mfma_f32_16x16x32_bf16(a0, qf0, S[mt], 0, 0, 0);
                short8 a1 = *(const short8*)(kb + mt * 16 * PIT + 32);
                S[mt] = __builtin_amdgcn_mfma_f32_16x16x32_bf16(a1, qf1, S[mt], 0, 0, 0);
            }
        }
        if (j0 + 63 > q0 + w * 16) {
            #pragma unroll
            for (int mt = 0; mt < 4; ++mt)
                #pragma unroll
                for (int r = 0; r < 4; ++r) {
                    int key = j0 + mt * 16 + quad * 4 + r;
                    if (key > qrow) S[mt][r] = NEG_BIG;
                }
        }
        float rmax = S[0][0];
        #pragma unroll
        for (int mt = 0; mt < 4; ++mt)
            #pragma unroll
            for (int r = 0; r < 4; ++r) rmax = fmaxf(rmax, S[mt][r]);
        rmax = fmaxf(rmax, __shfl_xor(rmax, 16, 64));
        rmax = fmaxf(rmax, __shfl_xor(rmax, 32, 64));
        float mn = fmaxf(m, rmax);
        float alpha = __expf(m - mn);
        float P[4][4];
        float rsum = 0.0f;
        #pragma unroll
        for (int mt = 0; mt < 4; ++mt)
            #pragma unroll
            for (int r = 0; r < 4; ++r) {
                P[mt][r] = __expf(S[mt][r] - mn);
                rsum += P[mt][r];
            }
        rsum += __shfl_xor(rsum, 16, 64);
        rsum += __shfl_xor(rsum, 32, 64);
        l = l * alpha + rsum;
        m = mn;
        #pragma unroll
        for (int i = 0; i < 4; ++i) O[i] *= alpha;
        #pragma unroll
        for (int mt = 0; mt < 4; ++mt) {
            uint2 uu;
            uu.x = f2bf(P[mt][0]) | (f2bf(P[mt][1]) << 16);
            uu.y = f2bf(P[mt][2]) | (f2bf(P[mt][3]) << 16);
            *(uint2*)(Plw + col * PIT + mt * 16 + quad * 4) = uu;
        }
        asm volatile("s_waitcnt lgkmcnt(0)" ::: "memory");
        short8 pf0 = *(const short8*)(Plw + col * PIT + quad * 8);
        short8 pf1 = *(const short8*)(Plw + col * PIT + 32 + quad * 8);
        {
            const unsigned short* vb = Vl + col * PIT + quad * 8;
            #pragma unroll
            for (int mt = 0; mt < 4; ++mt) {
                short8 a0 = *(const short8*)(vb + mt * 16 * PIT);
                O[mt] = __builtin_amdgcn_mfma_f32_16x16x32_bf16(a0, pf0, O[mt], 0, 0, 0);
                short8 a1 = *(const short8*)(vb + mt * 16 * PIT + 32);
                O[mt] = __builtin_amdgcn_mfma_f32_16x16x32_bf16(a1, pf1, O[mt], 0, 0, 0);
            }
        }
        __syncthreads();
    }
    float rl = 1.0f / l;
    unsigned short* yp = y + ((size_t)b * Nn + qrow) * Ee + h * Dd;
    #pragma unroll
    for (int mt = 0; mt < 4; ++mt) {
        f32x4 o = O[mt] * rl;    // dims mt*16+quad*4 .. +3 of q-row `qrow`
        uint2 uu;
        uu.x = f2bf(o[0]) | (f2bf(o[1]) << 16);
        uu.y = f2bf(o[2]) | (f2bf(o[3]) << 16);
        *(uint2*)(yp + mt * 16 + quad * 4) = uu;
    }
}

// MFMA NT GEMM: out[m][e] = sum_f y[m][f]*W[e][f] + bias[e]
// 128x128 tile, BK=64, 4 waves 2x2, each 64x64 via 4x4 of 16x16x32 bf16 MFMAs.
__global__ __launch_bounds__(256) void proj_kernel(
    const unsigned short* __restrict__ y, const unsigned short* __restrict__ w,
    const float* __restrict__ bias, float* __restrict__ out)
{
    __shared__ __align__(16) unsigned short Al[128 * PIT];
    __shared__ __align__(16) unsigned short Bl[128 * PIT];
    int t = threadIdx.x;
    int wv = t >> 6, lane = t & 63;
    int quad = lane >> 4, col = lane & 15;
    int wm = wv >> 1, wn = wv & 1;
    int e0 = blockIdx.x * 128, m0 = blockIdx.y * 128;
    f32x4 acc[4][4];
    #pragma unroll
    for (int i = 0; i < 4; ++i)
        #pragma unroll
        for (int j = 0; j < 4; ++j) acc[i][j] = (f32x4){0.f, 0.f, 0.f, 0.f};

    for (int k0 = 0; k0 < Ee; k0 += 64) {
        #pragma unroll
        for (int c = 0; c < 4; ++c) {
            int id = t + c * 256;                 // 0..1023 chunks of 8 bf16
            int row = id >> 3, e8 = (id & 7) * 8;
            *(uint4*)(Al + row * PIT + e8) =
                *(const uint4*)(y + (size_t)(m0 + row) * Ee + k0 + e8);
            *(uint4*)(Bl + row * PIT + e8) =
                *(const uint4*)(w + (size_t)(e0 + row) * Ee + k0 + e8);
        }
        __syncthreads();
        #pragma unroll
        for (int kc = 0; kc < 2; ++kc) {
            short8 a[4], bb[4];
            #pragma unroll
            for (int mi = 0; mi < 4; ++mi)
                a[mi] = *(const short8*)(Al + (wm * 64 + mi * 16 + col) * PIT + kc * 32 + quad * 8);
            #pragma unroll
            for (int ni = 0; ni < 4; ++ni)
                bb[ni] = *(const short8*)(Bl + (wn * 64 + ni * 16 + col) * PIT + kc * 32 + quad * 8);
            #pragma unroll
            for (int mi = 0; mi < 4; ++mi)
                #pragma unroll
                for (int ni = 0; ni < 4; ++ni)
                    acc[mi][ni] = __builtin_amdgcn_mfma_f32_16x16x32_bf16(a[mi], bb[ni], acc[mi][ni], 0, 0, 0);
        }
        __syncthreads();
    }
    // C layout: e-col = col, m-row = quad*4 + r
    #pragma unroll
    for (int ni = 0; ni < 4; ++ni) {
        int e = e0 + wn * 64 + ni * 16 + col;
        float be = bias[e];
        #pragma unroll
        for (int mi = 0; mi < 4; ++mi) {
            int mrow = m0 + wm * 64 + mi * 16 + quad * 4;
            #pragma unroll
            for (int r = 0; r < 4; ++r)
                out[(size_t)(mrow + r) * Ee + e] = acc[mi][ni][r] + be;
        }
    }
}

extern "C" void kernel_launch(void* const* d_in, const int* in_sizes, int n_in,
                              void* d_out, int out_size, void* d_ws, size_t ws_size,
                              hipStream_t stream) {
    const float* q      = (const float*)d_in[0];
    const float* k      = (const float*)d_in[1];
    const float* v      = (const float*)d_in[2];
    const float* qscale = (const float*)d_in[3];
    const float* kscale = (const float*)d_in[4];
    const float* projw  = (const float*)d_in[5];
    const float* projb  = (const float*)d_in[6];
    float* out = (float*)d_out;

    char* base = (char*)d_ws;
    float* ctab  = (float*)(base);                       // 3 x 128 KB
    float* stab  = (float*)(base + 131072);
    float* sctab = (float*)(base + 262144);
    unsigned short* qn   = (unsigned short*)(base + 393216);      // 12.58 MB each
    unsigned short* kn   = (unsigned short*)(base + 12976128);
    unsigned short* vt   = (unsigned short*)(base + 25559040);
    unsigned short* yatt = (unsigned short*)(base + 38141952);    // bf16 now
    unsigned short* wb   = (unsigned short*)(base + 50724864);    // 1.18 MB

    tab_kernel<<<(Nn * 16 + 255) / 256, 256, 0, stream>>>(ctab, stab, sctab);
    prep_kernel<<<(Bb * Hh * Nn) / 4, 256, 0, stream>>>(
        q, k, qscale, kscale, ctab, stab, sctab, qn, kn);
    vt_kernel<<<Bb * Hh * 32, 256, 0, stream>>>(v, vt);
    wcvt_kernel<<<(Ee * Ee / 4) / 256, 256, 0, stream>>>(projw, wb);

    dim3 agrid(Nn / 64, Bb * Hh);                        // (32, 48)
    attn_kernel<<<agrid, 256, 0, stream>>>(qn, kn, vt, yatt);

    dim3 ggrid(Ee / 128, (Bb * Nn) / 128);               // (6, 64)
    proj_kernel<<<ggrid, 256, 0, stream>>>(yatt, wb, projb, out);
}